// Round 11
// baseline (453.200 us; speedup 1.0000x reference)
//
#include <hip/hip_runtime.h>

// SamClip: N=1024 binary masks (256x256 fp32), scores[1024].
// out int32: [0:1024] = order (argsort desc, stable), [1024:2048] = keep (0/1).
//
// R11: 3-dispatch pipeline.
//  K1 pack_init: bitpack in ORIGINAL order (4096 blocks, quarter-mask each,
//     per-block areaQ slot - no atomics); blocks 0..3 also run the stable
//     argsort; block 4 zeroes the combine counter.
//  K2 pair: LDS-free i8 MFMA Gram tiles (R10 core) with per-lane order[]
//     row gather (indirection moved here from pack).
//  K3 combine_keep: R10 combine + atomic-counter last-block runs keep.

#define NM 1024
#define HW 65536
#define WPR 2048          // u32 words per packed row
#define NT 8              // 8x8 grid of 128-row tiles
#define NPAIRS 36         // NT*(NT+1)/2
#define KQ 16             // k-split: each pair block covers 128 words (4096 bits)

typedef float vfloat4 __attribute__((ext_vector_type(4)));
typedef int v4i __attribute__((ext_vector_type(4)));
typedef int v16i __attribute__((ext_vector_type(16)));

__device__ __forceinline__ void tile_from_pair(int p, int& I, int& J) {
    int rem = p, i = 0;
    while (rem >= NT - i) { rem -= NT - i; ++i; }
    I = i; J = i + rem;
}

// expand 16 bits of `word` starting at bit `sh` into 16 0/1 bytes (v4i)
__device__ __forceinline__ v4i expand16(unsigned word, int sh) {
    v4i r;
    r[0] = (int)((((word >> (sh + 0))  & 0xFu) * 0x00204081u) & 0x01010101u);
    r[1] = (int)((((word >> (sh + 4))  & 0xFu) * 0x00204081u) & 0x01010101u);
    r[2] = (int)((((word >> (sh + 8))  & 0xFu) * 0x00204081u) & 0x01010101u);
    r[3] = (int)((((word >> (sh + 12)) & 0xFu) * 0x00204081u) & 0x01010101u);
    return r;
}

// ---------------- Kernel 1: pack (original order) + sort + init ----------------
__global__ __launch_bounds__(256) void pack_init_kernel(const float* __restrict__ masks,
                                                        const float* __restrict__ scores,
                                                        unsigned* __restrict__ packed,
                                                        unsigned* __restrict__ areaQ,
                                                        int* __restrict__ order,
                                                        float* __restrict__ ssort,
                                                        int* __restrict__ out_order,
                                                        unsigned* __restrict__ ioumax,
                                                        unsigned* __restrict__ innu,
                                                        unsigned* __restrict__ innl,
                                                        unsigned* __restrict__ counter) {
    __shared__ int red[4];
    __shared__ float s[NM];

    const int b = blockIdx.x;
    const int r = b >> 2, q = b & 3;
    const vfloat4* __restrict__ row = (const vfloat4*)(masks + (size_t)r * HW) + q * 4096;
    unsigned* __restrict__ prow = packed + (size_t)r * WPR + q * 512;
    const int t = threadIdx.x;

    vfloat4 f[16];
    #pragma unroll
    for (int k = 0; k < 16; ++k)
        f[k] = __builtin_nontemporal_load(row + k * 256 + t);

    unsigned w0 = 0u, w1 = 0u;
    #pragma unroll
    for (int k = 0; k < 8; ++k) {
        const unsigned nib0 = (unsigned)(f[k][0] != 0.0f)        | ((unsigned)(f[k][1] != 0.0f) << 1)
                            | ((unsigned)(f[k][2] != 0.0f) << 2) | ((unsigned)(f[k][3] != 0.0f) << 3);
        w0 |= nib0 << (k * 4);
        const unsigned nib1 = (unsigned)(f[k + 8][0] != 0.0f)        | ((unsigned)(f[k + 8][1] != 0.0f) << 1)
                            | ((unsigned)(f[k + 8][2] != 0.0f) << 2) | ((unsigned)(f[k + 8][3] != 0.0f) << 3);
        w1 |= nib1 << (k * 4);
    }
    prow[t] = w0;
    prow[256 + t] = w1;

    int cnt = __builtin_popcount(w0) + __builtin_popcount(w1);
    for (int off = 32; off > 0; off >>= 1) cnt += __shfl_down(cnt, off, 64);
    const int lane = t & 63, w = t >> 6;
    if (lane == 0) red[w] = cnt;
    __syncthreads();
    if (t == 0) areaQ[b] = (unsigned)(red[0] + red[1] + red[2] + red[3]);

    if (b < 4) {       // stable descending argsort (4 blocks x 256 ranks)
        for (int k = t; k < NM; k += 256) s[k] = scores[k];
        __syncthreads();
        const int i = b * 256 + t;
        const float si = s[i];
        int rank = 0;
        #pragma unroll 8
        for (int j = 0; j < NM; ++j) {
            const float sj = s[j];
            rank += (int)((sj > si) || (sj == si && j < i));
        }
        order[rank] = i;
        ssort[rank] = si;
        out_order[rank] = i;
        ioumax[i] = 0u; innu[i] = 0u; innl[i] = 0u;
    }
    if (b == 4 && t == 0) *counter = 0u;
}

// ---------------- Kernel 2: pairwise inter via i8 MFMA, LDS-free ----------------
// Block (p, kq): 128x128 tile pair p (I<=J) in SORTED index space; packed rows
// gathered via order[]. 4 waves = output quadrants; 2x2 mfma_i32_32x32x32_i8
// tiles; bits->bytes in registers. C/D: col=lane&31,
// row=(reg&3)+8*(reg>>2)+4*(lane>>5)  [guide §3, m74/m101].
__global__ __launch_bounds__(256, 3) void pair_kernel(const unsigned* __restrict__ packed,
                                                      const int* __restrict__ order,
                                                      int* __restrict__ partial) {
    const int p = blockIdx.x, kq = blockIdx.y;
    int I, J; tile_from_pair(p, I, J);
    const int A0 = I * 128, B0 = J * 128;
    const int t = threadIdx.x;
    const int wave = t >> 6, lane = t & 63, half = lane >> 5, lr = lane & 31;
    const int wr = (wave >> 1) * 64, wc = (wave & 1) * 64;

    // diagonal tile: quadrant rows 64..127 x cols 0..63 is entirely a>b -> unused
    if (I == J && wave == 2) return;

    const unsigned* __restrict__ rowA0 = packed + (size_t)order[A0 + wr + lr] * WPR + kq * 128;
    const unsigned* __restrict__ rowA1 = packed + (size_t)order[A0 + wr + 32 + lr] * WPR + kq * 128;
    const unsigned* __restrict__ rowB0 = packed + (size_t)order[B0 + wc + lr] * WPR + kq * 128;
    const unsigned* __restrict__ rowB1 = packed + (size_t)order[B0 + wc + 32 + lr] * WPR + kq * 128;
    const int sh = half * 16;

    v16i acc[2][2];
    #pragma unroll
    for (int i = 0; i < 2; ++i)
        #pragma unroll
        for (int j = 0; j < 2; ++j)
            #pragma unroll
            for (int r = 0; r < 16; ++r) acc[i][j][r] = 0;

    #pragma unroll 2
    for (int g = 0; g < 32; ++g) {
        const uint4 wa0 = *(const uint4*)(rowA0 + g * 4);
        const uint4 wa1 = *(const uint4*)(rowA1 + g * 4);
        const uint4 wb0 = *(const uint4*)(rowB0 + g * 4);
        const uint4 wb1 = *(const uint4*)(rowB1 + g * 4);
        const unsigned a0w[4] = { wa0.x, wa0.y, wa0.z, wa0.w };
        const unsigned a1w[4] = { wa1.x, wa1.y, wa1.z, wa1.w };
        const unsigned b0w[4] = { wb0.x, wb0.y, wb0.z, wb0.w };
        const unsigned b1w[4] = { wb1.x, wb1.y, wb1.z, wb1.w };
        #pragma unroll
        for (int w = 0; w < 4; ++w) {
            const v4i a0 = expand16(a0w[w], sh);
            const v4i a1 = expand16(a1w[w], sh);
            const v4i b0 = expand16(b0w[w], sh);
            const v4i b1 = expand16(b1w[w], sh);
            acc[0][0] = __builtin_amdgcn_mfma_i32_32x32x32_i8(a0, b0, acc[0][0], 0, 0, 0);
            acc[0][1] = __builtin_amdgcn_mfma_i32_32x32x32_i8(a0, b1, acc[0][1], 0, 0, 0);
            acc[1][0] = __builtin_amdgcn_mfma_i32_32x32x32_i8(a1, b0, acc[1][0], 0, 0, 0);
            acc[1][1] = __builtin_amdgcn_mfma_i32_32x32x32_i8(a1, b1, acc[1][1], 0, 0, 0);
        }
    }

    int* __restrict__ outp = partial + ((size_t)kq * NPAIRS + p) * 16384;
    #pragma unroll
    for (int i = 0; i < 2; ++i)
        #pragma unroll
        for (int j = 0; j < 2; ++j)
            #pragma unroll
            for (int reg = 0; reg < 16; ++reg) {
                const int m = wr + i * 32 + (reg & 3) + 8 * (reg >> 2) + 4 * half;
                const int n = wc + j * 32 + lr;
                outp[m * 128 + n] = acc[i][j][reg];
            }
}

// ---------------- Kernel 3: combine + epilogue + column max + (last block) keep ----------------
__global__ __launch_bounds__(256) void combine_keep_kernel(const unsigned* __restrict__ partial,
                                                           const unsigned* __restrict__ areaQ,
                                                           const int* __restrict__ order,
                                                           const float* __restrict__ ssort,
                                                           unsigned* __restrict__ ioumax,
                                                           unsigned* __restrict__ innu,
                                                           unsigned* __restrict__ innl,
                                                           unsigned* __restrict__ counter,
                                                           int* __restrict__ out_keep) {
    __shared__ unsigned redI[128], redU[128], redLB[128], redLA[8];
    __shared__ float aB[128];
    __shared__ unsigned done;

    const int p = blockIdx.x, rg = blockIdx.y;
    int I, J; tile_from_pair(p, I, J);
    const int A0 = I * 128, B0 = J * 128;
    const int t = threadIdx.x;
    if (t < 128) {
        redI[t] = 0u; redU[t] = 0u; redLB[t] = 0u;
        const int id = order[B0 + t];
        aB[t] = (float)(areaQ[4 * id] + areaQ[4 * id + 1] + areaQ[4 * id + 2] + areaQ[4 * id + 3]);
    }
    if (t < 8) redLA[t] = 0u;
    __syncthreads();

    const int row = rg * 8 + (t >> 5);
    const int col = (t & 31) * 4;
    const int a = A0 + row;
    const int ida = order[a];
    const float fa = (float)(areaQ[4 * ida] + areaQ[4 * ida + 1] + areaQ[4 * ida + 2] + areaQ[4 * ida + 3]);

    unsigned sx = 0, sy = 0, sz = 0, sw = 0;
    #pragma unroll
    for (int kq = 0; kq < KQ; ++kq) {
        const uint4 v = *(const uint4*)(partial + ((size_t)kq * NPAIRS + p) * 16384 + row * 128 + col);
        sx += v.x; sy += v.y; sz += v.z; sw += v.w;
    }
    const unsigned sums[4] = { sx, sy, sz, sw };

    float mLA = 0.0f;
    #pragma unroll
    for (int j = 0; j < 4; ++j) {
        const int b = B0 + col + j;
        if (a > b) continue;
        const float inter = (float)sums[j];
        const float fb = aB[col + j];
        const float uni = (fb + fa) - inter;
        const float iou = inter / (uni + 1e-8f);
        const float ra = inter / (fa + 1e-8f);        // ratio_i (row a)
        const float rb = inter / (fb + 1e-8f);        // ratio_j (col b)
        const float v = __fsub_rn(1.0f, __fmul_rn(rb, ra));
        const float iab = (ra < 0.5f && rb >= 0.85f) ? v : 0.0f;
        const float iba = (rb < 0.5f && ra >= 0.85f) ? v : 0.0f;
        if (a < b) {
            atomicMax(&redI[col + j], __float_as_uint(iou));
            atomicMax(&redU[col + j], __float_as_uint(iab));   // inner[a,b] -> innu[b]
            mLA = fmaxf(mLA, iba);                             // inner[b,a] -> innl[a]
        }
        if (a == b - 1) atomicMax(&redLB[col + j], __float_as_uint(iab)); // superdiag -> innl[b]
    }
    atomicMax(&redLA[t >> 5], __float_as_uint(mLA));
    __syncthreads();
    if (t < 128) {
        atomicMax(&ioumax[B0 + t], redI[t]);
        atomicMax(&innu[B0 + t], redU[t]);
        atomicMax(&innl[B0 + t], redLB[t]);
    }
    if (t < 8) atomicMax(&innl[A0 + rg * 8 + t], redLA[t]);

    // last block runs keep (device-scope counter; atomic reads for coherence)
    __threadfence();
    if (t == 0) done = atomicAdd(counter, 1u);
    __syncthreads();
    if (done == (unsigned)(NPAIRS * KQ - 1)) {
        __threadfence();
        const float s0 = ssort[0];
        for (int r = t; r < NM; r += 256) {
            const bool conf = (s0 > 0.7f) ? (ssort[r] > 0.7f) : (r < 3);
            const unsigned vi = atomicOr(ioumax + r, 0u);
            const unsigned vu = atomicOr(innu + r, 0u);
            const unsigned vl = atomicOr(innl + r, 0u);
            const bool keep = (__uint_as_float(vi) <= 0.8f) && conf &&
                              (__uint_as_float(vu) <= 0.5f) &&
                              (__uint_as_float(vl) <= 0.5f);
            out_keep[r] = keep ? 1 : 0;
        }
    }
}

extern "C" void kernel_launch(void* const* d_in, const int* in_sizes, int n_in,
                              void* d_out, int out_size, void* d_ws, size_t ws_size,
                              hipStream_t stream) {
    const float* masks  = (const float*)d_in[0];
    const float* scores = (const float*)d_in[1];
    int* out = (int*)d_out;

    unsigned* packed  = (unsigned*)d_ws;                        // 8 MB
    unsigned* partial = packed + (size_t)NM * WPR;              // 16*36*16384 u32 = 37.75 MB
    unsigned* tail    = partial + (size_t)KQ * NPAIRS * 16384;
    int*      order   = (int*)tail;                             // 1024
    float*    ssort   = (float*)(order + NM);                   // 1024
    unsigned* areaQ   = (unsigned*)(ssort + NM);                // 4096
    unsigned* ioumax  = areaQ + 4 * NM;                         // 1024
    unsigned* innu    = ioumax + NM;
    unsigned* innl    = innu + NM;
    unsigned* counter = innl + NM;

    pack_init_kernel<<<4096, 256, 0, stream>>>(masks, scores, packed, areaQ, order, ssort,
                                               out, ioumax, innu, innl, counter);
    pair_kernel<<<dim3(NPAIRS, KQ), 256, 0, stream>>>(packed, order, (int*)partial);
    combine_keep_kernel<<<dim3(NPAIRS, KQ), 256, 0, stream>>>(partial, areaQ, order, ssort,
                                                              ioumax, innu, innl, counter,
                                                              out + NM);
}

// Round 12
// 428.859 us; speedup vs baseline: 1.0568x; 1.0568x over previous
//
#include <hip/hip_runtime.h>

// SamClip: N=1024 binary masks (256x256 fp32), scores[1024].
// out int32: [0:1024] = order (argsort desc, stable), [1024:2048] = keep (0/1).
//
// R12 = R10 verbatim (best verified: 430.1 us). R11's fusion regressed 23 us
// (pair's order[] gather destroyed L2 locality of the packed-row reads).
// Structure: sort -> pack (sorted order, NT loads, quarter-mask blocks)
// -> LDS-free i8-MFMA pair (registers: bits->bytes expand, 2x2 32x32x32
// tiles/wave, diagonal-quadrant skip) -> combine -> keep.

#define N_MASKS 1024
#define HW 65536
#define WPR 2048          // u32 words per packed row
#define NT 8              // 8x8 grid of 128-row tiles
#define NPAIRS 36         // NT*(NT+1)/2
#define KQ 16             // k-split: each pair block covers 128 words (4096 bits)

typedef float vfloat4 __attribute__((ext_vector_type(4)));
typedef int v4i __attribute__((ext_vector_type(4)));
typedef int v16i __attribute__((ext_vector_type(16)));

__device__ __forceinline__ void tile_from_pair(int p, int& I, int& J) {
    int rem = p, i = 0;
    while (rem >= NT - i) { rem -= NT - i; ++i; }
    I = i; J = i + rem;
}

// expand 16 bits of `word` starting at bit `sh` into 16 0/1 bytes (v4i)
__device__ __forceinline__ v4i expand16(unsigned word, int sh) {
    v4i r;
    r[0] = (int)((((word >> (sh + 0))  & 0xFu) * 0x00204081u) & 0x01010101u);
    r[1] = (int)((((word >> (sh + 4))  & 0xFu) * 0x00204081u) & 0x01010101u);
    r[2] = (int)((((word >> (sh + 8))  & 0xFu) * 0x00204081u) & 0x01010101u);
    r[3] = (int)((((word >> (sh + 12)) & 0xFu) * 0x00204081u) & 0x01010101u);
    return r;
}

// ---------------- Kernel A: stable descending argsort + init ----------------
__global__ __launch_bounds__(128) void sort_kernel(const float* __restrict__ scores,
                                                   int* __restrict__ order,
                                                   float* __restrict__ ssort,
                                                   int* __restrict__ out_order,
                                                   float* __restrict__ area,
                                                   unsigned* __restrict__ ioumax,
                                                   unsigned* __restrict__ innu,
                                                   unsigned* __restrict__ innl) {
    __shared__ float s[N_MASKS];
    const int t = threadIdx.x;
    for (int k = t; k < N_MASKS; k += 128) s[k] = scores[k];
    __syncthreads();
    const int i = blockIdx.x * 128 + t;
    const float si = s[i];
    int rank = 0;
    #pragma unroll 8
    for (int j = 0; j < N_MASKS; ++j) {
        const float sj = s[j];
        rank += (int)((sj > si) || (sj == si && j < i));
    }
    order[rank] = i;
    ssort[rank] = si;
    out_order[rank] = i;
    area[i] = 0.0f;
    ioumax[i] = 0u; innu[i] = 0u; innl[i] = 0u;
}

// ---------------- Kernel B: bitpack (sorted order) + area ----------------
__global__ __launch_bounds__(256, 4) void pack_kernel(const float* __restrict__ masks,
                                                      const int* __restrict__ order,
                                                      unsigned* __restrict__ packed,
                                                      float* __restrict__ area) {
    const int b = blockIdx.x;
    const int r = b >> 2, q = b & 3;
    const int src = order[r];
    const vfloat4* __restrict__ row = (const vfloat4*)(masks + (size_t)src * HW) + q * 4096;
    unsigned* __restrict__ prow = packed + (size_t)r * WPR + q * 512;
    const int t = threadIdx.x;

    vfloat4 f[16];
    #pragma unroll
    for (int k = 0; k < 16; ++k)
        f[k] = __builtin_nontemporal_load(row + k * 256 + t);

    unsigned w0 = 0u, w1 = 0u;
    #pragma unroll
    for (int k = 0; k < 8; ++k) {
        const unsigned nib0 = (unsigned)(f[k][0] != 0.0f)        | ((unsigned)(f[k][1] != 0.0f) << 1)
                            | ((unsigned)(f[k][2] != 0.0f) << 2) | ((unsigned)(f[k][3] != 0.0f) << 3);
        w0 |= nib0 << (k * 4);
        const unsigned nib1 = (unsigned)(f[k + 8][0] != 0.0f)        | ((unsigned)(f[k + 8][1] != 0.0f) << 1)
                            | ((unsigned)(f[k + 8][2] != 0.0f) << 2) | ((unsigned)(f[k + 8][3] != 0.0f) << 3);
        w1 |= nib1 << (k * 4);
    }
    prow[t] = w0;
    prow[256 + t] = w1;

    int cnt = __builtin_popcount(w0) + __builtin_popcount(w1);
    for (int off = 32; off > 0; off >>= 1) cnt += __shfl_down(cnt, off, 64);
    __shared__ int red[4];
    const int lane = t & 63, w = t >> 6;
    if (lane == 0) red[w] = cnt;
    __syncthreads();
    if (t == 0) atomicAdd(area + r, (float)(red[0] + red[1] + red[2] + red[3]));
}

// ---------------- Kernel C: pairwise inter via i8 MFMA, LDS-free ----------------
// Block (p, kq): 128x128 tile pair p (I<=J), k-range = 128 packed words.
// 4 waves: quadrants (wr,wc) in {0,64}^2; each wave = 2x2 mfma_i32_32x32x32_i8
// tiles, full k-range. Per group of 4 k-steps: 4 uint4 per-lane loads from L2,
// register expansion, 16 MFMA. A-frag: row=lane&31, k-bytes=(lane>>5)*16+[0,16);
// C/D: col=lane&31, row=(reg&3)+8*(reg>>2)+4*(lane>>5)  [guide §3, m74/m101].
__global__ __launch_bounds__(256, 3) void pair_kernel(const unsigned* __restrict__ packed,
                                                      int* __restrict__ partial) {
    const int p = blockIdx.x, kq = blockIdx.y;
    int I, J; tile_from_pair(p, I, J);
    const int A0 = I * 128, B0 = J * 128;
    const int t = threadIdx.x;
    const int wave = t >> 6, lane = t & 63, half = lane >> 5, lr = lane & 31;
    const int wr = (wave >> 1) * 64, wc = (wave & 1) * 64;

    // diagonal tile: quadrant rows 64..127 x cols 0..63 is entirely a>b -> unused
    if (I == J && wave == 2) return;

    const unsigned* __restrict__ rowA0 = packed + (size_t)(A0 + wr + lr) * WPR + kq * 128;
    const unsigned* __restrict__ rowA1 = rowA0 + 32 * WPR;
    const unsigned* __restrict__ rowB0 = packed + (size_t)(B0 + wc + lr) * WPR + kq * 128;
    const unsigned* __restrict__ rowB1 = rowB0 + 32 * WPR;
    const int sh = half * 16;

    v16i acc[2][2];
    #pragma unroll
    for (int i = 0; i < 2; ++i)
        #pragma unroll
        for (int j = 0; j < 2; ++j)
            #pragma unroll
            for (int r = 0; r < 16; ++r) acc[i][j][r] = 0;

    #pragma unroll 2
    for (int g = 0; g < 32; ++g) {
        const uint4 wa0 = *(const uint4*)(rowA0 + g * 4);
        const uint4 wa1 = *(const uint4*)(rowA1 + g * 4);
        const uint4 wb0 = *(const uint4*)(rowB0 + g * 4);
        const uint4 wb1 = *(const uint4*)(rowB1 + g * 4);
        const unsigned a0w[4] = { wa0.x, wa0.y, wa0.z, wa0.w };
        const unsigned a1w[4] = { wa1.x, wa1.y, wa1.z, wa1.w };
        const unsigned b0w[4] = { wb0.x, wb0.y, wb0.z, wb0.w };
        const unsigned b1w[4] = { wb1.x, wb1.y, wb1.z, wb1.w };
        #pragma unroll
        for (int w = 0; w < 4; ++w) {
            const v4i a0 = expand16(a0w[w], sh);
            const v4i a1 = expand16(a1w[w], sh);
            const v4i b0 = expand16(b0w[w], sh);
            const v4i b1 = expand16(b1w[w], sh);
            acc[0][0] = __builtin_amdgcn_mfma_i32_32x32x32_i8(a0, b0, acc[0][0], 0, 0, 0);
            acc[0][1] = __builtin_amdgcn_mfma_i32_32x32x32_i8(a0, b1, acc[0][1], 0, 0, 0);
            acc[1][0] = __builtin_amdgcn_mfma_i32_32x32x32_i8(a1, b0, acc[1][0], 0, 0, 0);
            acc[1][1] = __builtin_amdgcn_mfma_i32_32x32x32_i8(a1, b1, acc[1][1], 0, 0, 0);
        }
    }

    int* __restrict__ outp = partial + ((size_t)kq * NPAIRS + p) * 16384;
    #pragma unroll
    for (int i = 0; i < 2; ++i)
        #pragma unroll
        for (int j = 0; j < 2; ++j)
            #pragma unroll
            for (int reg = 0; reg < 16; ++reg) {
                const int m = wr + i * 32 + (reg & 3) + 8 * (reg >> 2) + 4 * half;
                const int n = wc + j * 32 + lr;
                outp[m * 128 + n] = acc[i][j][reg];
            }
}

// ---------------- Kernel D: combine partials + epilogue + column max ----------------
__global__ __launch_bounds__(256) void combine_kernel(const unsigned* __restrict__ partial,
                                                      const float* __restrict__ area,
                                                      unsigned* __restrict__ ioumax,
                                                      unsigned* __restrict__ innu,
                                                      unsigned* __restrict__ innl) {
    __shared__ unsigned redI[128], redU[128], redLB[128], redLA[8];
    __shared__ float aB[128];

    const int p = blockIdx.x, rg = blockIdx.y;
    int I, J; tile_from_pair(p, I, J);
    const int A0 = I * 128, B0 = J * 128;
    const int t = threadIdx.x;
    if (t < 128) { redI[t] = 0u; redU[t] = 0u; redLB[t] = 0u; aB[t] = area[B0 + t]; }
    if (t < 8) redLA[t] = 0u;
    __syncthreads();

    const int row = rg * 8 + (t >> 5);
    const int col = (t & 31) * 4;
    const int a = A0 + row;
    const float fa = area[a];

    unsigned sx = 0, sy = 0, sz = 0, sw = 0;
    #pragma unroll
    for (int kq = 0; kq < KQ; ++kq) {
        const uint4 v = *(const uint4*)(partial + ((size_t)kq * NPAIRS + p) * 16384 + row * 128 + col);
        sx += v.x; sy += v.y; sz += v.z; sw += v.w;
    }
    const unsigned sums[4] = { sx, sy, sz, sw };

    float mLA = 0.0f;
    #pragma unroll
    for (int j = 0; j < 4; ++j) {
        const int b = B0 + col + j;
        if (a > b) continue;
        const float inter = (float)sums[j];
        const float fb = aB[col + j];
        const float uni = (fb + fa) - inter;
        const float iou = inter / (uni + 1e-8f);
        const float ra = inter / (fa + 1e-8f);        // ratio_i (row a)
        const float rb = inter / (fb + 1e-8f);        // ratio_j (col b)
        const float v = __fsub_rn(1.0f, __fmul_rn(rb, ra));
        const float iab = (ra < 0.5f && rb >= 0.85f) ? v : 0.0f;
        const float iba = (rb < 0.5f && ra >= 0.85f) ? v : 0.0f;
        if (a < b) {
            atomicMax(&redI[col + j], __float_as_uint(iou));
            atomicMax(&redU[col + j], __float_as_uint(iab));   // inner[a,b] -> innu[b]
            mLA = fmaxf(mLA, iba);                             // inner[b,a] -> innl[a]
        }
        if (a == b - 1) atomicMax(&redLB[col + j], __float_as_uint(iab)); // superdiag -> innl[b]
    }
    atomicMax(&redLA[t >> 5], __float_as_uint(mLA));
    __syncthreads();
    if (t < 128) {
        atomicMax(&ioumax[B0 + t], redI[t]);
        atomicMax(&innu[B0 + t], redU[t]);
        atomicMax(&innl[B0 + t], redLB[t]);
    }
    if (t < 8) atomicMax(&innl[A0 + rg * 8 + t], redLA[t]);
}

// ---------------- Kernel E: final keep ----------------
__global__ __launch_bounds__(256) void keep_kernel(const float* __restrict__ ssort,
                                                   const unsigned* __restrict__ ioumax,
                                                   const unsigned* __restrict__ innu,
                                                   const unsigned* __restrict__ innl,
                                                   int* __restrict__ out_keep) {
    const int r = blockIdx.x * 256 + threadIdx.x;
    const float s0 = ssort[0];
    const bool conf = (s0 > 0.7f) ? (ssort[r] > 0.7f) : (r < 3);
    const bool keep = (__uint_as_float(ioumax[r]) <= 0.8f) && conf &&
                      (__uint_as_float(innu[r]) <= 0.5f) &&
                      (__uint_as_float(innl[r]) <= 0.5f);
    out_keep[r] = keep ? 1 : 0;
}

extern "C" void kernel_launch(void* const* d_in, const int* in_sizes, int n_in,
                              void* d_out, int out_size, void* d_ws, size_t ws_size,
                              hipStream_t stream) {
    const float* masks  = (const float*)d_in[0];
    const float* scores = (const float*)d_in[1];
    int* out = (int*)d_out;

    unsigned* packed  = (unsigned*)d_ws;                        // 8 MB
    unsigned* partial = packed + (size_t)N_MASKS * WPR;         // 16*36*16384 u32 = 37.75 MB
    unsigned* tail    = partial + (size_t)KQ * NPAIRS * 16384;
    int*      order   = (int*)tail;
    float*    ssort   = (float*)(order + N_MASKS);
    float*    area    = (float*)(ssort + N_MASKS);
    unsigned* ioumax  = (unsigned*)(area + N_MASKS);
    unsigned* innu    = ioumax + N_MASKS;
    unsigned* innl    = innu + N_MASKS;

    sort_kernel<<<8, 128, 0, stream>>>(scores, order, ssort, out, area, ioumax, innu, innl);
    pack_kernel<<<4096, 256, 0, stream>>>(masks, order, packed, area);
    pair_kernel<<<dim3(NPAIRS, KQ), 256, 0, stream>>>(packed, (int*)partial);
    combine_kernel<<<dim3(NPAIRS, KQ), 256, 0, stream>>>(partial, area, ioumax, innu, innl);
    keep_kernel<<<4, 256, 0, stream>>>(ssort, ioumax, innu, innl, out + N_MASKS);
}